// Round 1
// baseline (222.615 us; speedup 1.0000x reference)
//
#include <hip/hip_runtime.h>

// GatherFromIndices: out[b,n,k,:] = k<K ? (inds[b,n,k]>=0 ? inp[b, inds[b,n,k]%N, :] : 0)
//                                  : inp[b,n,:]        (self slot, k==K)
// Shapes: inp [B,N,F] f32, inds [B,N,K] i32, out [B,N,K+1,F] f32.

constexpr int B   = 8;
constexpr int N   = 10000;
constexpr int F   = 64;       // 16 float4 per row
constexpr int K   = 8;
constexpr int KP1 = K + 1;
constexpr int ROWS = B * N * KP1;          // 720000 output rows of 256 B

__global__ __launch_bounds__(256)
void GatherFromIndices_kernel(const float* __restrict__ inp,
                              const int*   __restrict__ inds,
                              float*       __restrict__ out) {
    // 16 threads per output row; each thread moves one float4 (16 B).
    int t    = blockIdx.x * 256 + threadIdx.x;
    int r    = t >> 4;        // output row index in [0, ROWS)
    int lane = t & 15;        // float4 slot within the 64-float row

    if (r >= ROWS) return;    // grid is exact (45000 blocks), kept for safety

    int k  = r % KP1;         // neighbor slot (K == self)
    int bn = r / KP1;         // flat (b*N + n)

    float4 v;
    if (k == K) {
        // self features
        v = ((const float4*)(inp + (size_t)bn * F))[lane];
    } else {
        int idx = inds[bn * K + k];
        if (idx < 0) {
            v = make_float4(0.f, 0.f, 0.f, 0.f);   // MASK_VALUE row
        } else {
            int b   = bn / N;
            int row = b * N + (idx % N);           // faithful to (idx % N) + seq_offset
            v = ((const float4*)(inp + (size_t)row * F))[lane];
        }
    }
    ((float4*)out)[(size_t)r * 16 + lane] = v;
}

extern "C" void kernel_launch(void* const* d_in, const int* in_sizes, int n_in,
                              void* d_out, int out_size, void* d_ws, size_t ws_size,
                              hipStream_t stream) {
    const float* inp  = (const float*)d_in[0];
    const int*   inds = (const int*)d_in[1];
    float*       out  = (float*)d_out;

    // ROWS * 16 threads total = 11,520,000 = 45,000 blocks of 256 exactly.
    int total_threads = ROWS * 16;
    int blocks = (total_threads + 255) / 256;
    GatherFromIndices_kernel<<<blocks, 256, 0, stream>>>(inp, inds, out);
}